// Round 7
// baseline (6988.217 us; speedup 1.0000x reference)
//
#include <hip/hip_runtime.h>
#include <hip/hip_bf16.h>

#define Bz 32
#define Tz 1024
#define Iz 64
#define Hz 512
#define Az 16

// d_out layout (FP32 elems): out [B,T,A] | hn [1,B,H] | rnn_out [B,T,H]
#define OFF_HN  (Bz*Tz*Az)
#define OFF_RNN (OFF_HN + Bz*Hz)

typedef unsigned short u16;
typedef unsigned int u32;
typedef unsigned long long u64;
typedef __attribute__((ext_vector_type(8))) unsigned short u16x8;
typedef __attribute__((ext_vector_type(8))) __bf16 bf16x8;
typedef __attribute__((ext_vector_type(4))) float f32x4;

// ws layout (bytes) — no flags, no ring (zero inter-block communication)
#define WS_WIH  0x00000u  // u16[64*512] bf16 (layout-preserved)      = 64 KB
#define WS_WHT  0x10000u  // u16[512*512] bf16 whhT [n][k]            = 512 KB
#define WS_W1T  0x90000u  // u16[512*512] bf16 w1t [n][k]; end 0x110000

__device__ __forceinline__ u16 f2bf(float f) {
  union { float f; unsigned int i; } x; x.f = f;
  unsigned int r = (x.i + 0x7FFFu + ((x.i >> 16) & 1u)) >> 16;
  return (u16)r;
}
__device__ __forceinline__ float bf2f(u16 u) {
  union { unsigned int i; float f; } x; x.i = ((unsigned int)u) << 16; return x.f;
}
__device__ __forceinline__ float sigmoidf_(float z) {
  return 1.0f / (1.0f + __expf(-z));
}

// ---------------------------------------------------------------------------
// Prep: fp32 -> bf16 copies. whhT and w1t TRANSPOSED to [n][k].
// ---------------------------------------------------------------------------
__global__ void prep_kernel(const float* __restrict__ whh,
                            const float* __restrict__ wih,
                            const float* __restrict__ w1,
                            u16* __restrict__ whhT,
                            u16* __restrict__ wih_bf,
                            u16* __restrict__ w1t_bf) {
  int idx = blockIdx.x * 256 + threadIdx.x;
  if (idx < 262144) {
    int n = idx >> 9, k = idx & 511;
    whhT[idx] = f2bf(whh[k * Hz + n]);        // whhT[n][k] <- whh[k][n]
  } else if (idx < 294912) {
    int i = idx - 262144;
    wih_bf[i] = f2bf(wih[i]);
  } else if (idx < 557056) {
    int j = idx - 294912;
    int n = j >> 9, k = j & 511;
    w1t_bf[n * Hz + k] = f2bf(w1[k * Hz + n]);  // [n][k] <- [k][n]
  }
}

// ---------------------------------------------------------------------------
// xproj: out_rnn[b*T+t][n] = sum_i inp[b][t][i] * wih[i][n]  (fp32 result).
// Scan reads this per step and overwrites it in place with h_t.
// ---------------------------------------------------------------------------
__global__ __launch_bounds__(256, 2) void xproj_kernel(
    const float* __restrict__ inp,   // [32768 rows][64]
    const u16* __restrict__ wih_bf,  // [i=64][n=512]
    float* __restrict__ xp)          // [32768][512] (= out_rnn region)
{
  __shared__ u16 wl[512][72];  // col-major [n][i], pad 8 -> 73,728 B

  const int tid  = threadIdx.x;
  const int lane = tid & 63;
  const int wv   = tid >> 6;
  const int ln   = lane & 15;
  const int q    = lane >> 4;

#pragma unroll
  for (int i = 0; i < Iz; ++i) {
    wl[tid][i]       = wih_bf[i * Hz + tid];
    wl[tid + 256][i] = wih_bf[i * Hz + tid + 256];
  }
  __syncthreads();

  const size_t row0 = (size_t)blockIdx.x * 64 + wv * 16;
  const float* ip = inp + (row0 + ln) * Iz + q * 8;
  f32x4 x0 = *(const f32x4*)(ip);
  f32x4 x1 = *(const f32x4*)(ip + 4);
  f32x4 x2 = *(const f32x4*)(ip + 32);
  f32x4 x3 = *(const f32x4*)(ip + 36);
  u16x8 ax0, ax1;
#pragma unroll
  for (int j = 0; j < 4; ++j) {
    ax0[j]     = f2bf(x0[j]);
    ax0[4 + j] = f2bf(x1[j]);
    ax1[j]     = f2bf(x2[j]);
    ax1[4 + j] = f2bf(x3[j]);
  }

  for (int nt = 0; nt < 32; ++nt) {
    bf16x8 b0 = __builtin_bit_cast(bf16x8, *(const u16x8*)&wl[nt * 16 + ln][q * 8]);
    bf16x8 b1 = __builtin_bit_cast(bf16x8, *(const u16x8*)&wl[nt * 16 + ln][32 + q * 8]);
    f32x4 a = {0.f, 0.f, 0.f, 0.f};
    a = __builtin_amdgcn_mfma_f32_16x16x32_bf16(
        __builtin_bit_cast(bf16x8, ax0), b0, a, 0, 0, 0);
    a = __builtin_amdgcn_mfma_f32_16x16x32_bf16(
        __builtin_bit_cast(bf16x8, ax1), b1, a, 0, 0, 0);
#pragma unroll
    for (int r = 0; r < 4; ++r)
      xp[(row0 + q * 4 + r) * Hz + nt * 16 + ln] = a[r];
  }
}

// ---------------------------------------------------------------------------
// Scan R13: 2 blocks x 512 thr (8 waves), zero inter-block communication.
// R12 post-mortem: demanded residency (bhh 192 + acc 16 + ~60 transients >
// 256-reg/wave cap at 2 waves/SIMD) -> compiler REMATERIALIZED overflow bhh
// from whhT(L2) every step (WRITE_SIZE==outputs exactly -> no scratch; VGPR
// 128 + needed AGPR 208 > 256 -> impossible). ~2000+ stall cyc/step.
// Fix: three-way W_hh split with an EXPLICIT per-step stream:
//   - k in [0,256):   bhh[4 ct][8 ks] registers (128 frag regs; acc in AGPR)
//   - k in [256,384): streamed per step from whhT via VOLATILE b128 loads
//                     (volatile defeats LICM re-hoisting = the R12 failure),
//                     issued 2 k-slices ahead of use -> L2 latency hidden
//   - k in [384,512): LDS wlds[512][136] (unchanged)
// Accumulation order: ks 0..7 (reg), ks 8,9 (stream1), ks 12..15 (LDS),
// ks 10,11 (stream2 last, covering its latency). fp32 reorder: 5x absmax
// headroom, safe.
// hlds stride 528 -> 544 (272 dw = 16 mod 32: A-read b128 is perfectly
// bank-balanced, zero extra conflict).
// MFMA 16x16x32 bf16 (HW-proven): A m=lane&15,k=q*8+j; B n=lane&15,k=q*8+j;
//                                 C/D col=lane&15, row=q*4+reg.
// ---------------------------------------------------------------------------
__global__ __launch_bounds__(512, 2) void rnn_scan_kernel(
    const float* __restrict__ hn,    // [B][H] fp32
    const u16* __restrict__ whhT,    // [n=H][k=H] bf16
    float* __restrict__ out_rnn,     // [B][T][H] fp32, pre-filled with xproj
    float* __restrict__ out_hn)      // [B][H] fp32
{
  __shared__ u16 wlds[512][136];  // W_hh k in [384,512), col-major: 139,264 B
  __shared__ u16 hlds[16][544];   // h_t [row][gcol], stride 544:    17,408 B

  const int tid  = threadIdx.x;
  const int lane = tid & 63;
  const int w    = tid >> 6;      // wave 0..7 -> cols [64w, 64w+64)
  const int ln   = lane & 15;
  const int q    = lane >> 4;
  const int r0   = blockIdx.x * 16;
  const int c0   = w * 64;

  // ---- W_hh k in [0,256) -> registers (128 frag regs)
  bf16x8 bhh[4][8];
#pragma unroll
  for (int ct = 0; ct < 4; ++ct)
#pragma unroll
    for (int ks = 0; ks < 8; ++ks)
      bhh[ct][ks] = __builtin_bit_cast(
          bf16x8, *(const u16x8*)(whhT + (size_t)(c0 + ct * 16 + ln) * Hz +
                                  ks * 32 + q * 8));

  // ---- stream base pointers for k in [256,384): 4 per-ct lane pointers
  const u16* wsp[4];
#pragma unroll
  for (int ct = 0; ct < 4; ++ct)
    wsp[ct] = whhT + (size_t)(c0 + ct * 16 + ln) * Hz + 256 + q * 8;

  // ---- W_hh k in [384,512) -> LDS (col = tid; 16 x u16x8 = 128 elements)
#pragma unroll
  for (int j = 0; j < 16; ++j)
    *(u16x8*)&wlds[tid][j * 8] =
        *(const u16x8*)(whhT + (size_t)tid * Hz + 384 + j * 8);

  // ---- h0 -> LDS
  {
    const int row = tid >> 5, c = (tid & 31) * 16;
    const float* hp = hn + (size_t)(r0 + row) * Hz + c;
    f32x4 a0 = *(const f32x4*)(hp);
    f32x4 a1 = *(const f32x4*)(hp + 4);
    f32x4 a2 = *(const f32x4*)(hp + 8);
    f32x4 a3 = *(const f32x4*)(hp + 12);
    u16x8 p0, p1;
#pragma unroll
    for (int j = 0; j < 4; ++j) {
      p0[j] = f2bf(a0[j]); p0[4 + j] = f2bf(a1[j]);
      p1[j] = f2bf(a2[j]); p1[4 + j] = f2bf(a3[j]);
    }
    *(u16x8*)&hlds[row][c]     = p0;
    *(u16x8*)&hlds[row][c + 8] = p1;
  }
  __syncthreads();

  for (int t = 0; t < Tz; ++t) {
    // Phase 1: issue stream batch 1 (ks 8,9) — volatile pins issue point
    u16x8 s1[4][2];
#pragma unroll
    for (int ct = 0; ct < 4; ++ct) {
      s1[ct][0] = *(volatile const u16x8*)(wsp[ct]);
      s1[ct][1] = *(volatile const u16x8*)(wsp[ct] + 32);
    }

    f32x4 acc[4];
#pragma unroll
    for (int ct = 0; ct < 4; ++ct) acc[ct] = (f32x4){0.f, 0.f, 0.f, 0.f};

    // Phase 2: k in [0,256) — A from h-LDS, B from registers
#pragma unroll
    for (int ks = 0; ks < 8; ++ks) {
      bf16x8 A = __builtin_bit_cast(
          bf16x8, *(const u16x8*)&hlds[ln][ks * 32 + q * 8]);
#pragma unroll
      for (int ct = 0; ct < 4; ++ct)
        acc[ct] = __builtin_amdgcn_mfma_f32_16x16x32_bf16(
            A, bhh[ct][ks], acc[ct], 0, 0, 0);
    }

    // Phase 3: issue xp loads (consumed at epilogue)
    float xp[4][4];
#pragma unroll
    for (int r = 0; r < 4; ++r) {
      const float* xrow =
          out_rnn + ((size_t)(r0 + q * 4 + r) * Tz + t) * Hz + c0 + ln;
#pragma unroll
      for (int ct = 0; ct < 4; ++ct) xp[ct][r] = xrow[ct * 16];
    }

    // Phase 4: k in [256,320) — stream batch 1 (latency covered by phase 2)
#pragma unroll
    for (int s = 0; s < 2; ++s) {
      bf16x8 A = __builtin_bit_cast(
          bf16x8, *(const u16x8*)&hlds[ln][(8 + s) * 32 + q * 8]);
#pragma unroll
      for (int ct = 0; ct < 4; ++ct)
        acc[ct] = __builtin_amdgcn_mfma_f32_16x16x32_bf16(
            A, __builtin_bit_cast(bf16x8, s1[ct][s]), acc[ct], 0, 0, 0);
    }

    // Phase 5: issue stream batch 2 (ks 10,11)
    u16x8 s2[4][2];
#pragma unroll
    for (int ct = 0; ct < 4; ++ct) {
      s2[ct][0] = *(volatile const u16x8*)(wsp[ct] + 64);
      s2[ct][1] = *(volatile const u16x8*)(wsp[ct] + 96);
    }

    // Phase 6: k in [384,512) — A from h-LDS, B from W-LDS (covers batch 2)
#pragma unroll
    for (int lk = 0; lk < 4; ++lk) {
      bf16x8 A = __builtin_bit_cast(
          bf16x8, *(const u16x8*)&hlds[ln][(12 + lk) * 32 + q * 8]);
#pragma unroll
      for (int ct = 0; ct < 4; ++ct) {
        bf16x8 Bf = __builtin_bit_cast(
            bf16x8, *(const u16x8*)&wlds[c0 + ct * 16 + ln][lk * 32 + q * 8]);
        acc[ct] = __builtin_amdgcn_mfma_f32_16x16x32_bf16(
            A, Bf, acc[ct], 0, 0, 0);
      }
    }

    // Phase 7: k in [320,384) — stream batch 2, consumed last
#pragma unroll
    for (int s = 0; s < 2; ++s) {
      bf16x8 A = __builtin_bit_cast(
          bf16x8, *(const u16x8*)&hlds[ln][(10 + s) * 32 + q * 8]);
#pragma unroll
      for (int ct = 0; ct < 4; ++ct)
        acc[ct] = __builtin_amdgcn_mfma_f32_16x16x32_bf16(
            A, __builtin_bit_cast(bf16x8, s2[ct][s]), acc[ct], 0, 0, 0);
    }

    // Epilogue: h = sigmoid(acc + xp)
    float hv[4][4];
#pragma unroll
    for (int ct = 0; ct < 4; ++ct)
#pragma unroll
      for (int r = 0; r < 4; ++r) hv[ct][r] = sigmoidf_(acc[ct][r] + xp[ct][r]);

    __syncthreads();  // all waves' h_t A-reads complete before overwrite

#pragma unroll
    for (int ct = 0; ct < 4; ++ct)
#pragma unroll
      for (int r = 0; r < 4; ++r) {
        u32 mine  = (u32)f2bf(hv[ct][r]);
        u32 other = (u32)__shfl_xor((int)mine, 1, 64);
        if (!(ln & 1))
          *(u32*)&hlds[q * 4 + r][c0 + ct * 16 + ln] = mine | (other << 16);
      }
    __syncthreads();  // h_{t+1} visible to all waves

    // overwrite the xp slot with h (off critical path)
#pragma unroll
    for (int r = 0; r < 4; ++r) {
      float* orow =
          out_rnn + ((size_t)(r0 + q * 4 + r) * Tz + t) * Hz + c0 + ln;
#pragma unroll
      for (int ct = 0; ct < 4; ++ct) orow[ct * 16] = hv[ct][r];
    }
    if (t == Tz - 1) {
#pragma unroll
      for (int r = 0; r < 4; ++r)
#pragma unroll
        for (int ct = 0; ct < 4; ++ct)
          out_hn[(size_t)(r0 + q * 4 + r) * Hz + c0 + ct * 16 + ln] = hv[ct][r];
    }
  }
}

// ---------------------------------------------------------------------------
// FC head (unchanged, R3-lineage).
// ---------------------------------------------------------------------------
__global__ __launch_bounds__(256, 2) void fc_kernel(
    const float* __restrict__ X,  // [32768][512] fp32 (= rnn_out)
    const u16* __restrict__ w1t,  // [n=512][k=512] bf16
    const float* __restrict__ b1, // [512] fp32
    const float* __restrict__ w2, // [n=512][a=16] fp32
    const float* __restrict__ b2, // [16] fp32
    float* __restrict__ out)      // [32768][16] fp32
{
  __shared__ u16 smem[18432];     // 36 KB
  u16* As = smem;                 // [128][72]
  u16* Bs = smem + 9216;          // [128][72]
  u16* Ht = smem;                 // [128][136] (reused, 34816 B)

  const int tid  = threadIdx.x;
  const int lane = tid & 63;
  const int wv   = tid >> 6;
  const int ln   = lane & 15, q = lane >> 4;
  const int mq   = (wv & 1) * 64, nq = (wv >> 1) * 64;
  const size_t r0 = (size_t)blockIdx.x * 128;
  const int om = tid >> 1;          // output row 0..127
  const int oa = (tid & 1) * 8;     // output col half

  float oacc[8];
#pragma unroll
  for (int j = 0; j < 8; ++j) oacc[j] = 0.f;

  for (int nt = 0; nt < 4; ++nt) {
    const int n0 = nt * 128;
    f32x4 acc[4][4];
#pragma unroll
    for (int mi = 0; mi < 4; ++mi)
#pragma unroll
      for (int ni = 0; ni < 4; ++ni) acc[mi][ni] = (f32x4){0.f, 0.f, 0.f, 0.f};

    for (int kb = 0; kb < 8; ++kb) {
      const int K0 = kb * 64;
      __syncthreads();  // prior frag/Ht reads done before restaging
      for (int i = tid; i < 1024; i += 256) {
        int row = i >> 3, c = (i & 7) * 8;
        f32x4 lo = *(const f32x4*)(X + (r0 + row) * Hz + K0 + c);
        f32x4 hi = *(const f32x4*)(X + (r0 + row) * Hz + K0 + c + 4);
        u16x8 pxx;
#pragma unroll
        for (int j = 0; j < 4; ++j) { pxx[j] = f2bf(lo[j]); pxx[4 + j] = f2bf(hi[j]); }
        *(u16x8*)(As + row * 72 + c) = pxx;
      }
      for (int i = tid; i < 1024; i += 256) {
        int row = i >> 3, c = (i & 7) * 8;
        *(u16x8*)(Bs + row * 72 + c) =
            *(const u16x8*)(w1t + (size_t)(n0 + row) * Hz + K0 + c);
      }
      __syncthreads();
#pragma unroll
      for (int kt = 0; kt < 2; ++kt) {
        bf16x8 af[4], bfr[4];
#pragma unroll
        for (int mi = 0; mi < 4; ++mi)
          af[mi] = __builtin_bit_cast(
              bf16x8,
              *(const u16x8*)(As + (mq + mi * 16 + ln) * 72 + kt * 32 + q * 8));
#pragma unroll
        for (int ni = 0; ni < 4; ++ni)
          bfr[ni] = __builtin_bit_cast(
              bf16x8,
              *(const u16x8*)(Bs + (nq + ni * 16 + ln) * 72 + kt * 32 + q * 8));
#pragma unroll
        for (int mi = 0; mi < 4; ++mi)
#pragma unroll
          for (int ni = 0; ni < 4; ++ni)
            acc[mi][ni] = __builtin_amdgcn_mfma_f32_16x16x32_bf16(
                af[mi], bfr[ni], acc[mi][ni], 0, 0, 0);
      }
    }
    __syncthreads();  // MFMA frag reads done before Ht overwrite

    // hidden = relu(acc + b1) -> Ht bf16
#pragma unroll
    for (int ni = 0; ni < 4; ++ni) {
      float bb = b1[n0 + nq + ni * 16 + ln];
#pragma unroll
      for (int mi = 0; mi < 4; ++mi)
#pragma unroll
        for (int r = 0; r < 4; ++r) {
          float h = fmaxf(acc[mi][ni][r] + bb, 0.f);
          Ht[(mq + mi * 16 + q * 4 + r) * 136 + nq + ni * 16 + ln] = f2bf(h);
        }
    }
    __syncthreads();

    // fc2 partial over this n-slice into registers
    for (int n = 0; n < 128; ++n) {
      float hv = bf2f(Ht[om * 136 + n]);
      const float* w2p = w2 + (size_t)(n0 + n) * Az + oa;
#pragma unroll
      for (int j = 0; j < 8; ++j) oacc[j] += hv * w2p[j];
    }
  }

#pragma unroll
  for (int j = 0; j < 8; ++j)
    out[(r0 + om) * Az + oa + j] = sigmoidf_(oacc[j] + b2[oa + j]);
}

extern "C" void kernel_launch(void* const* d_in, const int* in_sizes, int n_in,
                              void* d_out, int out_size, void* d_ws, size_t ws_size,
                              hipStream_t stream) {
  // Permutation detection from in_sizes (insurance; proven harmless)
  int idx_inp = 0, idx_hn = 1, idx_wih = 3, idx_b1 = 5, idx_w2 = 6, idx_b2 = 7;
  int amb1 = -1, amb2 = -1, found = 0;
  for (int i = 0; i < 8 && i < n_in; ++i) {
    switch (in_sizes[i]) {
      case 2097152: idx_inp = i; found |= 1; break;
      case 16384:   idx_hn  = i; found |= 2; break;
      case 32768:   idx_wih = i; found |= 4; break;
      case 512:     idx_b1  = i; found |= 8; break;
      case 8192:    idx_w2  = i; found |= 16; break;
      case 16:      idx_b2  = i; found |= 32; break;
      case 262144:  if (amb1 < 0) amb1 = i; else amb2 = i; break;
    }
  }
  int idx_whh = 2, idx_w1 = 4;  // dict-order fallback
  if (amb1 >= 0 && amb2 >= 0 && found == 63) {
    if (idx_b1 < idx_inp) { idx_w1 = amb1; idx_whh = amb2; }
    else                  { idx_whh = amb1; idx_w1 = amb2; }
  }

  const float* inp = (const float*)d_in[idx_inp];
  const float* hn  = (const float*)d_in[idx_hn];
  const float* whh = (const float*)d_in[idx_whh];
  const float* wih = (const float*)d_in[idx_wih];
  const float* w1  = (const float*)d_in[idx_w1];
  const float* b1  = (const float*)d_in[idx_b1];
  const float* w2  = (const float*)d_in[idx_w2];
  const float* b2  = (const float*)d_in[idx_b2];

  float* out     = (float*)d_out;
  float* out_hn  = out + OFF_HN;
  float* out_rnn = out + OFF_RNN;

  char* ws    = (char*)d_ws;
  u16* wih_bf = (u16*)(ws + WS_WIH);
  u16* whhT   = (u16*)(ws + WS_WHT);
  u16* w1t_bf = (u16*)(ws + WS_W1T);

  prep_kernel<<<dim3(2176), dim3(256), 0, stream>>>(whh, wih, w1,
                                                    whhT, wih_bf, w1t_bf);
  xproj_kernel<<<dim3(512), dim3(256), 0, stream>>>(inp, wih_bf, out_rnn);
  rnn_scan_kernel<<<dim3(2), dim3(512), 0, stream>>>(
      hn, whhT, out_rnn, out_hn);
  fc_kernel<<<dim3(256), dim3(256), 0, stream>>>(
      out_rnn, w1t_bf, b1, w2, b2, out);
}

// Round 8
// 6211.078 us; speedup vs baseline: 1.1251x; 1.1251x over previous
//
#include <hip/hip_runtime.h>
#include <hip/hip_bf16.h>

#define Bz 32
#define Tz 1024
#define Iz 64
#define Hz 512
#define Az 16

// d_out layout (FP32 elems): out [B,T,A] | hn [1,B,H] | rnn_out [B,T,H]
#define OFF_HN  (Bz*Tz*Az)
#define OFF_RNN (OFF_HN + Bz*Hz)

typedef unsigned short u16;
typedef unsigned int u32;
typedef unsigned long long u64;
typedef __attribute__((ext_vector_type(8))) unsigned short u16x8;
typedef __attribute__((ext_vector_type(8))) __bf16 bf16x8;
typedef __attribute__((ext_vector_type(4))) float f32x4;

// ws layout (bytes) — no flags, no ring (zero inter-block communication)
#define WS_WIH  0x00000u  // u16[64*512] bf16 (layout-preserved)      = 64 KB
#define WS_WHT  0x10000u  // u16[512*512] bf16 whhT [n][k]            = 512 KB
#define WS_W1T  0x90000u  // u16[512*512] bf16 w1t [n][k]; end 0x110000

__device__ __forceinline__ u16 f2bf(float f) {
  union { float f; unsigned int i; } x; x.f = f;
  unsigned int r = (x.i + 0x7FFFu + ((x.i >> 16) & 1u)) >> 16;
  return (u16)r;
}
__device__ __forceinline__ float bf2f(u16 u) {
  union { unsigned int i; float f; } x; x.i = ((unsigned int)u) << 16; return x.f;
}
__device__ __forceinline__ float sigmoidf_(float z) {
  return 1.0f / (1.0f + __expf(-z));
}

// ---------------------------------------------------------------------------
// Prep: fp32 -> bf16 copies. whhT and w1t TRANSPOSED to [n][k].
// ---------------------------------------------------------------------------
__global__ void prep_kernel(const float* __restrict__ whh,
                            const float* __restrict__ wih,
                            const float* __restrict__ w1,
                            u16* __restrict__ whhT,
                            u16* __restrict__ wih_bf,
                            u16* __restrict__ w1t_bf) {
  int idx = blockIdx.x * 256 + threadIdx.x;
  if (idx < 262144) {
    int n = idx >> 9, k = idx & 511;
    whhT[idx] = f2bf(whh[k * Hz + n]);        // whhT[n][k] <- whh[k][n]
  } else if (idx < 294912) {
    int i = idx - 262144;
    wih_bf[i] = f2bf(wih[i]);
  } else if (idx < 557056) {
    int j = idx - 294912;
    int n = j >> 9, k = j & 511;
    w1t_bf[n * Hz + k] = f2bf(w1[k * Hz + n]);  // [n][k] <- [k][n]
  }
}

// ---------------------------------------------------------------------------
// xproj: out_rnn[b*T+t][n] = sum_i inp[b][t][i] * wih[i][n]  (fp32 result).
// Scan reads this per step and overwrites it in place with h_t.
// ---------------------------------------------------------------------------
__global__ __launch_bounds__(256, 2) void xproj_kernel(
    const float* __restrict__ inp,   // [32768 rows][64]
    const u16* __restrict__ wih_bf,  // [i=64][n=512]
    float* __restrict__ xp)          // [32768][512] (= out_rnn region)
{
  __shared__ u16 wl[512][72];  // col-major [n][i], pad 8 -> 73,728 B

  const int tid  = threadIdx.x;
  const int lane = tid & 63;
  const int wv   = tid >> 6;
  const int ln   = lane & 15;
  const int q    = lane >> 4;

#pragma unroll
  for (int i = 0; i < Iz; ++i) {
    wl[tid][i]       = wih_bf[i * Hz + tid];
    wl[tid + 256][i] = wih_bf[i * Hz + tid + 256];
  }
  __syncthreads();

  const size_t row0 = (size_t)blockIdx.x * 64 + wv * 16;
  const float* ip = inp + (row0 + ln) * Iz + q * 8;
  f32x4 x0 = *(const f32x4*)(ip);
  f32x4 x1 = *(const f32x4*)(ip + 4);
  f32x4 x2 = *(const f32x4*)(ip + 32);
  f32x4 x3 = *(const f32x4*)(ip + 36);
  u16x8 ax0, ax1;
#pragma unroll
  for (int j = 0; j < 4; ++j) {
    ax0[j]     = f2bf(x0[j]);
    ax0[4 + j] = f2bf(x1[j]);
    ax1[j]     = f2bf(x2[j]);
    ax1[4 + j] = f2bf(x3[j]);
  }

  for (int nt = 0; nt < 32; ++nt) {
    bf16x8 b0 = __builtin_bit_cast(bf16x8, *(const u16x8*)&wl[nt * 16 + ln][q * 8]);
    bf16x8 b1 = __builtin_bit_cast(bf16x8, *(const u16x8*)&wl[nt * 16 + ln][32 + q * 8]);
    f32x4 a = {0.f, 0.f, 0.f, 0.f};
    a = __builtin_amdgcn_mfma_f32_16x16x32_bf16(
        __builtin_bit_cast(bf16x8, ax0), b0, a, 0, 0, 0);
    a = __builtin_amdgcn_mfma_f32_16x16x32_bf16(
        __builtin_bit_cast(bf16x8, ax1), b1, a, 0, 0, 0);
#pragma unroll
    for (int r = 0; r < 4; ++r)
      xp[(row0 + q * 4 + r) * Hz + nt * 16 + ln] = a[r];
  }
}

// ---------------------------------------------------------------------------
// Scan R14: 2 blocks x 512 thr (8 waves), zero inter-block communication.
// History: R12 demanded 192-frag-reg residency -> demand ~270 > 256 unified
// regs/wave -> compiler rematerialized the overflow from L2 unscheduled
// (8180 cyc/step). R13's volatile stream serialized the loads (13.5k).
// R14: honest three-way split with demand ~225 <= 256:
//   - k in [0,256):   bhh[4 ct][8 ks] = 128 frag regs (loop-resident)
//   - k in [256,384): streamed per step as NORMAL vector loads whose base
//     pointers are copied through an empty asm volatile each iteration
//     (defeats LICM re-hoisting -> no remat pressure, keeps compiler
//     waitcnts/scheduling). Two 8-load batches: b1 issued at step top,
//     consumed after the 32-MFMA register phase; b2 issue pinned after
//     b1 consumption via a data-dependent re-opaque, consumed last under
//     the wlds phase's cover.
//   - k in [384,512): LDS wlds[512][136] (unchanged)
// Accumulation order: ks0-7 (reg), ks8-9 (b1), ks12-15 (LDS), ks10-11 (b2),
// + xp. fp32 reorder: safe (5x absmax headroom).
// MFMA 16x16x32 bf16 (HW-proven): A m=lane&15,k=q*8+j; B n=lane&15,k=q*8+j;
//                                 C/D col=lane&15, row=q*4+reg.
// ---------------------------------------------------------------------------
__global__ __launch_bounds__(512, 1) void rnn_scan_kernel(
    const float* __restrict__ hn,    // [B][H] fp32
    const u16* __restrict__ whhT,    // [n=H][k=H] bf16
    float* __restrict__ out_rnn,     // [B][T][H] fp32, pre-filled with xproj
    float* __restrict__ out_hn)      // [B][H] fp32
{
  __shared__ u16 wlds[512][136];  // W_hh k in [384,512), col-major: 139,264 B
  __shared__ u16 hlds[16][528];   // h_t [row][gcol], stride 528:    16,896 B

  const int tid  = threadIdx.x;
  const int lane = tid & 63;
  const int w    = tid >> 6;      // wave 0..7 -> cols [64w, 64w+64)
  const int ln   = lane & 15;
  const int q    = lane >> 4;
  const int r0   = blockIdx.x * 16;
  const int c0   = w * 64;

  // ---- W_hh k in [0,256) -> registers (128 frag regs)
  bf16x8 bhh[4][8];
#pragma unroll
  for (int ct = 0; ct < 4; ++ct)
#pragma unroll
    for (int ks = 0; ks < 8; ++ks)
      bhh[ct][ks] = __builtin_bit_cast(
          bf16x8, *(const u16x8*)(whhT + (size_t)(c0 + ct * 16 + ln) * Hz +
                                  ks * 32 + q * 8));

  // ---- stream base addresses for k in [256,384): one per ct
  u64 wb0 = (u64)(whhT + (size_t)(c0 + 0 * 16 + ln) * Hz + 256 + q * 8);
  u64 wb1 = (u64)(whhT + (size_t)(c0 + 1 * 16 + ln) * Hz + 256 + q * 8);
  u64 wb2 = (u64)(whhT + (size_t)(c0 + 2 * 16 + ln) * Hz + 256 + q * 8);
  u64 wb3 = (u64)(whhT + (size_t)(c0 + 3 * 16 + ln) * Hz + 256 + q * 8);

  // ---- W_hh k in [384,512) -> LDS (col = tid; 16 x u16x8 = 128 elements)
#pragma unroll
  for (int j = 0; j < 16; ++j)
    *(u16x8*)&wlds[tid][j * 8] =
        *(const u16x8*)(whhT + (size_t)tid * Hz + 384 + j * 8);

  // ---- h0 -> LDS
  {
    const int row = tid >> 5, c = (tid & 31) * 16;
    const float* hp = hn + (size_t)(r0 + row) * Hz + c;
    f32x4 a0 = *(const f32x4*)(hp);
    f32x4 a1 = *(const f32x4*)(hp + 4);
    f32x4 a2 = *(const f32x4*)(hp + 8);
    f32x4 a3 = *(const f32x4*)(hp + 12);
    u16x8 p0, p1;
#pragma unroll
    for (int j = 0; j < 4; ++j) {
      p0[j] = f2bf(a0[j]); p0[4 + j] = f2bf(a1[j]);
      p1[j] = f2bf(a2[j]); p1[4 + j] = f2bf(a3[j]);
    }
    *(u16x8*)&hlds[row][c]     = p0;
    *(u16x8*)&hlds[row][c + 8] = p1;
  }
  __syncthreads();

  for (int t = 0; t < Tz; ++t) {
    // Opaque per-iteration copies of the stream pointers (defeats LICM —
    // this is the R12-remat fix; loads stay NORMAL compiler vector loads).
    u64 a0 = wb0, a1 = wb1, a2 = wb2, a3 = wb3;
    asm volatile("" : "+v"(a0), "+v"(a1), "+v"(a2), "+v"(a3));

    // Batch 1: ks 8,9 (k in [256,320)) — 8 dwordx4 loads, issued at top
    u16x8 s1[4][2];
    s1[0][0] = *(const u16x8*)(a0);  s1[0][1] = *(const u16x8*)((const u16*)a0 + 32);
    s1[1][0] = *(const u16x8*)(a1);  s1[1][1] = *(const u16x8*)((const u16*)a1 + 32);
    s1[2][0] = *(const u16x8*)(a2);  s1[2][1] = *(const u16x8*)((const u16*)a2 + 32);
    s1[3][0] = *(const u16x8*)(a3);  s1[3][1] = *(const u16x8*)((const u16*)a3 + 32);

    // xp loads (consumed at epilogue)
    float xp[4][4];
#pragma unroll
    for (int r = 0; r < 4; ++r) {
      const float* xrow =
          out_rnn + ((size_t)(r0 + q * 4 + r) * Tz + t) * Hz + c0 + ln;
#pragma unroll
      for (int ct = 0; ct < 4; ++ct) xp[ct][r] = xrow[ct * 16];
    }

    f32x4 acc[4];
#pragma unroll
    for (int ct = 0; ct < 4; ++ct) acc[ct] = (f32x4){0.f, 0.f, 0.f, 0.f};

    // Phase A: k in [0,256) — A from h-LDS, B from registers (32 MFMA;
    // covers batch-1 L2 latency)
#pragma unroll
    for (int ks = 0; ks < 8; ++ks) {
      bf16x8 A = __builtin_bit_cast(
          bf16x8, *(const u16x8*)&hlds[ln][ks * 32 + q * 8]);
#pragma unroll
      for (int ct = 0; ct < 4; ++ct)
        acc[ct] = __builtin_amdgcn_mfma_f32_16x16x32_bf16(
            A, bhh[ct][ks], acc[ct], 0, 0, 0);
    }

    // Phase B: consume batch 1 (ks 8,9)
#pragma unroll
    for (int s = 0; s < 2; ++s) {
      bf16x8 A = __builtin_bit_cast(
          bf16x8, *(const u16x8*)&hlds[ln][(8 + s) * 32 + q * 8]);
      acc[0] = __builtin_amdgcn_mfma_f32_16x16x32_bf16(
          A, __builtin_bit_cast(bf16x8, s1[0][s]), acc[0], 0, 0, 0);
      acc[1] = __builtin_amdgcn_mfma_f32_16x16x32_bf16(
          A, __builtin_bit_cast(bf16x8, s1[1][s]), acc[1], 0, 0, 0);
      acc[2] = __builtin_amdgcn_mfma_f32_16x16x32_bf16(
          A, __builtin_bit_cast(bf16x8, s1[2][s]), acc[2], 0, 0, 0);
      acc[3] = __builtin_amdgcn_mfma_f32_16x16x32_bf16(
          A, __builtin_bit_cast(bf16x8, s1[3][s]), acc[3], 0, 0, 0);
    }

    // Re-opaque with data dependence on acc[0]: pins batch-2 issue after
    // batch-1 consumption (keeps peak live regs ~225 < 256).
    asm volatile("" : "+v"(a0), "+v"(a1), "+v"(a2), "+v"(a3) : "v"(acc[0]));

    // Batch 2: ks 10,11 (k in [320,384)) — covered by the wlds phase
    u16x8 s2[4][2];
    s2[0][0] = *(const u16x8*)((const u16*)a0 + 64);  s2[0][1] = *(const u16x8*)((const u16*)a0 + 96);
    s2[1][0] = *(const u16x8*)((const u16*)a1 + 64);  s2[1][1] = *(const u16x8*)((const u16*)a1 + 96);
    s2[2][0] = *(const u16x8*)((const u16*)a2 + 64);  s2[2][1] = *(const u16x8*)((const u16*)a2 + 96);
    s2[3][0] = *(const u16x8*)((const u16*)a3 + 64);  s2[3][1] = *(const u16x8*)((const u16*)a3 + 96);

    // Phase C: k in [384,512) — A from h-LDS, B from W-LDS
#pragma unroll
    for (int lk = 0; lk < 4; ++lk) {
      bf16x8 A = __builtin_bit_cast(
          bf16x8, *(const u16x8*)&hlds[ln][(12 + lk) * 32 + q * 8]);
#pragma unroll
      for (int ct = 0; ct < 4; ++ct) {
        bf16x8 Bf = __builtin_bit_cast(
            bf16x8, *(const u16x8*)&wlds[c0 + ct * 16 + ln][lk * 32 + q * 8]);
        acc[ct] = __builtin_amdgcn_mfma_f32_16x16x32_bf16(
            A, Bf, acc[ct], 0, 0, 0);
      }
    }

    // Phase D: consume batch 2 (ks 10,11)
#pragma unroll
    for (int s = 0; s < 2; ++s) {
      bf16x8 A = __builtin_bit_cast(
          bf16x8, *(const u16x8*)&hlds[ln][(10 + s) * 32 + q * 8]);
      acc[0] = __builtin_amdgcn_mfma_f32_16x16x32_bf16(
          A, __builtin_bit_cast(bf16x8, s2[0][s]), acc[0], 0, 0, 0);
      acc[1] = __builtin_amdgcn_mfma_f32_16x16x32_bf16(
          A, __builtin_bit_cast(bf16x8, s2[1][s]), acc[1], 0, 0, 0);
      acc[2] = __builtin_amdgcn_mfma_f32_16x16x32_bf16(
          A, __builtin_bit_cast(bf16x8, s2[2][s]), acc[2], 0, 0, 0);
      acc[3] = __builtin_amdgcn_mfma_f32_16x16x32_bf16(
          A, __builtin_bit_cast(bf16x8, s2[3][s]), acc[3], 0, 0, 0);
    }

    // Epilogue: h = sigmoid(acc + xp)
    float hv[4][4];
#pragma unroll
    for (int ct = 0; ct < 4; ++ct)
#pragma unroll
      for (int r = 0; r < 4; ++r) hv[ct][r] = sigmoidf_(acc[ct][r] + xp[ct][r]);

    __syncthreads();  // all waves' h_t A-reads complete before overwrite

#pragma unroll
    for (int ct = 0; ct < 4; ++ct)
#pragma unroll
      for (int r = 0; r < 4; ++r) {
        u32 mine  = (u32)f2bf(hv[ct][r]);
        u32 other = (u32)__shfl_xor((int)mine, 1, 64);
        if (!(ln & 1))
          *(u32*)&hlds[q * 4 + r][c0 + ct * 16 + ln] = mine | (other << 16);
      }
    __syncthreads();  // h_{t+1} visible to all waves

    // overwrite the xp slot with h (off critical path)
#pragma unroll
    for (int r = 0; r < 4; ++r) {
      float* orow =
          out_rnn + ((size_t)(r0 + q * 4 + r) * Tz + t) * Hz + c0 + ln;
#pragma unroll
      for (int ct = 0; ct < 4; ++ct) orow[ct * 16] = hv[ct][r];
    }
    if (t == Tz - 1) {
#pragma unroll
      for (int r = 0; r < 4; ++r)
#pragma unroll
        for (int ct = 0; ct < 4; ++ct)
          out_hn[(size_t)(r0 + q * 4 + r) * Hz + c0 + ct * 16 + ln] = hv[ct][r];
    }
  }
}

// ---------------------------------------------------------------------------
// FC head (unchanged, R3-lineage).
// ---------------------------------------------------------------------------
__global__ __launch_bounds__(256, 2) void fc_kernel(
    const float* __restrict__ X,  // [32768][512] fp32 (= rnn_out)
    const u16* __restrict__ w1t,  // [n=512][k=512] bf16
    const float* __restrict__ b1, // [512] fp32
    const float* __restrict__ w2, // [n=512][a=16] fp32
    const float* __restrict__ b2, // [16] fp32
    float* __restrict__ out)      // [32768][16] fp32
{
  __shared__ u16 smem[18432];     // 36 KB
  u16* As = smem;                 // [128][72]
  u16* Bs = smem + 9216;          // [128][72]
  u16* Ht = smem;                 // [128][136] (reused, 34816 B)

  const int tid  = threadIdx.x;
  const int lane = tid & 63;
  const int wv   = tid >> 6;
  const int ln   = lane & 15, q = lane >> 4;
  const int mq   = (wv & 1) * 64, nq = (wv >> 1) * 64;
  const size_t r0 = (size_t)blockIdx.x * 128;
  const int om = tid >> 1;          // output row 0..127
  const int oa = (tid & 1) * 8;     // output col half

  float oacc[8];
#pragma unroll
  for (int j = 0; j < 8; ++j) oacc[j] = 0.f;

  for (int nt = 0; nt < 4; ++nt) {
    const int n0 = nt * 128;
    f32x4 acc[4][4];
#pragma unroll
    for (int mi = 0; mi < 4; ++mi)
#pragma unroll
      for (int ni = 0; ni < 4; ++ni) acc[mi][ni] = (f32x4){0.f, 0.f, 0.f, 0.f};

    for (int kb = 0; kb < 8; ++kb) {
      const int K0 = kb * 64;
      __syncthreads();  // prior frag/Ht reads done before restaging
      for (int i = tid; i < 1024; i += 256) {
        int row = i >> 3, c = (i & 7) * 8;
        f32x4 lo = *(const f32x4*)(X + (r0 + row) * Hz + K0 + c);
        f32x4 hi = *(const f32x4*)(X + (r0 + row) * Hz + K0 + c + 4);
        u16x8 pxx;
#pragma unroll
        for (int j = 0; j < 4; ++j) { pxx[j] = f2bf(lo[j]); pxx[4 + j] = f2bf(hi[j]); }
        *(u16x8*)(As + row * 72 + c) = pxx;
      }
      for (int i = tid; i < 1024; i += 256) {
        int row = i >> 3, c = (i & 7) * 8;
        *(u16x8*)(Bs + row * 72 + c) =
            *(const u16x8*)(w1t + (size_t)(n0 + row) * Hz + K0 + c);
      }
      __syncthreads();
#pragma unroll
      for (int kt = 0; kt < 2; ++kt) {
        bf16x8 af[4], bfr[4];
#pragma unroll
        for (int mi = 0; mi < 4; ++mi)
          af[mi] = __builtin_bit_cast(
              bf16x8,
              *(const u16x8*)(As + (mq + mi * 16 + ln) * 72 + kt * 32 + q * 8));
#pragma unroll
        for (int ni = 0; ni < 4; ++ni)
          bfr[ni] = __builtin_bit_cast(
              bf16x8,
              *(const u16x8*)(Bs + (nq + ni * 16 + ln) * 72 + kt * 32 + q * 8));
#pragma unroll
        for (int mi = 0; mi < 4; ++mi)
#pragma unroll
          for (int ni = 0; ni < 4; ++ni)
            acc[mi][ni] = __builtin_amdgcn_mfma_f32_16x16x32_bf16(
                af[mi], bfr[ni], acc[mi][ni], 0, 0, 0);
      }
    }
    __syncthreads();  // MFMA frag reads done before Ht overwrite

    // hidden = relu(acc + b1) -> Ht bf16
#pragma unroll
    for (int ni = 0; ni < 4; ++ni) {
      float bb = b1[n0 + nq + ni * 16 + ln];
#pragma unroll
      for (int mi = 0; mi < 4; ++mi)
#pragma unroll
        for (int r = 0; r < 4; ++r) {
          float h = fmaxf(acc[mi][ni][r] + bb, 0.f);
          Ht[(mq + mi * 16 + q * 4 + r) * 136 + nq + ni * 16 + ln] = f2bf(h);
        }
    }
    __syncthreads();

    // fc2 partial over this n-slice into registers
    for (int n = 0; n < 128; ++n) {
      float hv = bf2f(Ht[om * 136 + n]);
      const float* w2p = w2 + (size_t)(n0 + n) * Az + oa;
#pragma unroll
      for (int j = 0; j < 8; ++j) oacc[j] += hv * w2p[j];
    }
  }

#pragma unroll
  for (int j = 0; j < 8; ++j)
    out[(r0 + om) * Az + oa + j] = sigmoidf_(oacc[j] + b2[oa + j]);
}

extern "C" void kernel_launch(void* const* d_in, const int* in_sizes, int n_in,
                              void* d_out, int out_size, void* d_ws, size_t ws_size,
                              hipStream_t stream) {
  // Permutation detection from in_sizes (insurance; proven harmless)
  int idx_inp = 0, idx_hn = 1, idx_wih = 3, idx_b1 = 5, idx_w2 = 6, idx_b2 = 7;
  int amb1 = -1, amb2 = -1, found = 0;
  for (int i = 0; i < 8 && i < n_in; ++i) {
    switch (in_sizes[i]) {
      case 2097152: idx_inp = i; found |= 1; break;
      case 16384:   idx_hn  = i; found |= 2; break;
      case 32768:   idx_wih = i; found |= 4; break;
      case 512:     idx_b1  = i; found |= 8; break;
      case 8192:    idx_w2  = i; found |= 16; break;
      case 16:      idx_b2  = i; found |= 32; break;
      case 262144:  if (amb1 < 0) amb1 = i; else amb2 = i; break;
    }
  }
  int idx_whh = 2, idx_w1 = 4;  // dict-order fallback
  if (amb1 >= 0 && amb2 >= 0 && found == 63) {
    if (idx_b1 < idx_inp) { idx_w1 = amb1; idx_whh = amb2; }
    else                  { idx_whh = amb1; idx_w1 = amb2; }
  }

  const float* inp = (const float*)d_in[idx_inp];
  const float* hn  = (const float*)d_in[idx_hn];
  const float* whh = (const float*)d_in[idx_whh];
  const float* wih = (const float*)d_in[idx_wih];
  const float* w1  = (const float*)d_in[idx_w1];
  const float* b1  = (const float*)d_in[idx_b1];
  const float* w2  = (const float*)d_in[idx_w2];
  const float* b2  = (const float*)d_in[idx_b2];

  float* out     = (float*)d_out;
  float* out_hn  = out + OFF_HN;
  float* out_rnn = out + OFF_RNN;

  char* ws    = (char*)d_ws;
  u16* wih_bf = (u16*)(ws + WS_WIH);
  u16* whhT   = (u16*)(ws + WS_WHT);
  u16* w1t_bf = (u16*)(ws + WS_W1T);

  prep_kernel<<<dim3(2176), dim3(256), 0, stream>>>(whh, wih, w1,
                                                    whhT, wih_bf, w1t_bf);
  xproj_kernel<<<dim3(512), dim3(256), 0, stream>>>(inp, wih_bf, out_rnn);
  rnn_scan_kernel<<<dim3(2), dim3(512), 0, stream>>>(
      hn, whhT, out_rnn, out_hn);
  fc_kernel<<<dim3(256), dim3(256), 0, stream>>>(
      out_rnn, w1t_bf, b1, w2, b2, out);
}